// Round 2
// baseline (801.448 us; speedup 1.0000x reference)
//
#include <hip/hip_runtime.h>
#include <math.h>

#define BH 32
#define L  2048
#define D  64
#define SK 40
#define NT 40
#define SCALE 0.125f

// ---------------- Kernel A: sparse sampled scores -> M[bh*L + l] ----------------
// One wave per query. lane = d index. 40 sampled keys, butterfly-reduce each dot.
__global__ __launch_bounds__(256) void kM(const float* __restrict__ Q,
                                          const float* __restrict__ K,
                                          const int* __restrict__ idx,
                                          float* __restrict__ M)
{
    int wave = threadIdx.x >> 6;
    int lane = threadIdx.x & 63;
    int qid  = blockIdx.x * 4 + wave;          // 0 .. 65535
    int bh   = qid >> 11;
    int l    = qid & (L - 1);

    float qv = Q[(size_t)qid * D + lane];
    const float* Kb = K + (size_t)bh * L * D;

    float mx = -INFINITY, sm = 0.f;
    #pragma unroll 8
    for (int s = 0; s < SK; ++s) {
        int kr = idx[l * SK + s];
        float p = qv * Kb[(size_t)kr * D + lane];
        #pragma unroll
        for (int o = 32; o > 0; o >>= 1) p += __shfl_xor(p, o, 64);
        mx = fmaxf(mx, p);
        sm += p;
    }
    if (lane == 0) M[qid] = mx - sm * (1.0f / (float)L);
}

// ---------------- Kernel B: top-40 indices per head ----------------
__global__ __launch_bounds__(256) void kTop(const float* __restrict__ M, int* __restrict__ Mtop)
{
    __shared__ float sm[L];
    __shared__ float rv[256];
    __shared__ int   ri[256];
    int bh = blockIdx.x;
    int t  = threadIdx.x;
    for (int i = t; i < L; i += 256) sm[i] = M[bh * L + i];
    __syncthreads();
    for (int u = 0; u < NT; ++u) {
        float bv = -INFINITY; int bi = 0;
        for (int i = t; i < L; i += 256) {
            float v = sm[i];
            if (v > bv) { bv = v; bi = i; }   // strided scan keeps lowest local index on ties
        }
        rv[t] = bv; ri[t] = bi;
        __syncthreads();
        for (int s = 128; s > 0; s >>= 1) {
            if (t < s) {
                float ov = rv[t + s]; int oi = ri[t + s];
                if (ov > rv[t] || (ov == rv[t] && oi < ri[t])) { rv[t] = ov; ri[t] = oi; }
            }
            __syncthreads();
        }
        if (t == 0) { Mtop[bh * NT + u] = ri[0]; sm[ri[0]] = -INFINITY; }
        __syncthreads();
    }
}

// ---------------- Kernel C: per-head column mean of V ----------------
__global__ __launch_bounds__(256) void kVmean(const float* __restrict__ V,
                                              float* __restrict__ Vm)
{
    __shared__ float red[256];
    int bh = blockIdx.x;
    int d  = threadIdx.x & 63;
    int g  = threadIdx.x >> 6;                // 4 groups of 512 rows
    const float* Vb = V + (size_t)bh * L * D;
    float acc = 0.f;
    for (int j = g * 512; j < (g + 1) * 512; ++j) acc += Vb[(size_t)j * D + d];
    red[threadIdx.x] = acc;
    __syncthreads();
    if (threadIdx.x < 64) {
        float s = red[d] + red[64 + d] + red[128 + d] + red[192 + d];
        Vm[bh * D + d] = s * (1.0f / (float)L);
    }
}

// ---------------- Kernel D: broadcast V_mean into the whole output ----------------
__global__ __launch_bounds__(256) void kFill(const float* __restrict__ Vm,
                                             float* __restrict__ out)
{
    int tid  = blockIdx.x * 256 + threadIdx.x;    // 0 .. 1048575
    int base = tid * 4;                           // element index, 16B-aligned
    int bh   = base >> 17;                        // / (L*D) = 131072
    int d0   = base & (D - 1);                    // multiple of 4
    float4 v = *reinterpret_cast<const float4*>(Vm + bh * D + d0);
    *reinterpret_cast<float4*>(out + base) = v;
}

// ---------------- Kernel E: full attention for the 40 selected queries ----------------
// grid = (NT, BH). One block per (u, bh). Scores in LDS, fp32 softmax, coalesced PV.
__global__ __launch_bounds__(256) void kAttn(const float* __restrict__ Q,
                                             const float* __restrict__ K,
                                             const float* __restrict__ V,
                                             const int* __restrict__ Mtop,
                                             float* __restrict__ out)
{
    __shared__ float qs[D];
    __shared__ float sc[L];
    __shared__ float red[256];
    int u = blockIdx.x, bh = blockIdx.y;
    int t = threadIdx.x;
    int qrow = Mtop[bh * NT + u];

    if (t < D) qs[t] = Q[((size_t)bh * L + qrow) * D + t];
    __syncthreads();

    const float* Kb = K + (size_t)bh * L * D;
    float lmax = -INFINITY;
    for (int j = t; j < L; j += 256) {
        const float* kr = Kb + (size_t)j * D;
        float dot = 0.f;
        #pragma unroll
        for (int d4 = 0; d4 < D; d4 += 4) {
            float4 pk = *reinterpret_cast<const float4*>(kr + d4);
            dot += qs[d4 + 0] * pk.x + qs[d4 + 1] * pk.y
                 + qs[d4 + 2] * pk.z + qs[d4 + 3] * pk.w;
        }
        dot *= SCALE;
        sc[j] = dot;
        lmax = fmaxf(lmax, dot);
    }
    red[t] = lmax;
    __syncthreads();
    for (int s = 128; s > 0; s >>= 1) { if (t < s) red[t] = fmaxf(red[t], red[t + s]); __syncthreads(); }
    float gmax = red[0];
    __syncthreads();

    float lsum = 0.f;
    for (int j = t; j < L; j += 256) { float e = __expf(sc[j] - gmax); sc[j] = e; lsum += e; }
    red[t] = lsum;
    __syncthreads();
    for (int s = 128; s > 0; s >>= 1) { if (t < s) red[t] += red[t + s]; __syncthreads(); }
    float gsum = red[0];
    __syncthreads();

    // PV: thread = (d, j-group of 512)
    int d = t & 63, g = t >> 6;
    const float* Vb = V + (size_t)bh * L * D;
    float acc = 0.f;
    for (int j = g * 512; j < (g + 1) * 512; ++j) acc += sc[j] * Vb[(size_t)j * D + d];
    red[t] = acc;
    __syncthreads();
    if (t < 64) {
        float ctx = (red[t] + red[64 + t] + red[128 + t] + red[192 + t]) / gsum;
        out[((size_t)bh * L + qrow) * D + t] = ctx;
    }
}

extern "C" void kernel_launch(void* const* d_in, const int* in_sizes, int n_in,
                              void* d_out, int out_size, void* d_ws, size_t ws_size,
                              hipStream_t stream)
{
    const float* Q   = (const float*)d_in[0];
    const float* K   = (const float*)d_in[1];
    const float* V   = (const float*)d_in[2];
    const int*   idx = (const int*)d_in[3];
    float* out = (float*)d_out;

    float* M    = (float*)d_ws;                                      // 65536 f32 = 256 KB
    int*   Mtop = (int*)((char*)d_ws + (size_t)BH * L * 4);          // 1280 i32
    float* Vm   = (float*)((char*)d_ws + (size_t)BH * L * 4 + 8192); // 2048 f32

    kM    <<<(BH * L) / 4, 256, 0, stream>>>(Q, K, idx, M);
    kTop  <<<BH, 256, 0, stream>>>(M, Mtop);
    kVmean<<<BH, 256, 0, stream>>>(V, Vm);
    kFill <<<(BH * L * D) / (4 * 256), 256, 0, stream>>>(Vm, out);
    kAttn <<<dim3(NT, BH), 256, 0, stream>>>(Q, K, V, Mtop, out);
}

// Round 3
// 245.164 us; speedup vs baseline: 3.2690x; 3.2690x over previous
//
#include <hip/hip_runtime.h>
#include <math.h>

#define BH 32
#define L  2048
#define D  64
#define SK 40
#define NT 40
#define NC 16          // key chunks for split-K attention
#define CK 128         // keys per chunk (NC*CK == L)
#define SCALE 0.125f

// ---- workspace layout (bytes) --- total ~5.75 MB ----
#define WS_M      0                         // float[BH*L]          = 256 KB
#define WS_MTOP   262144                    // int[BH*NT]           = 5 KB
#define WS_VP     267264                    // float[256*64]        = 64 KB
#define WS_VM     332800                    // float[BH*D]          = 8 KB
#define WS_OPART  344064                    // float[BH*NC*NT*D]    = 5.24 MB
#define WS_MPART  5586944                   // float[BH*NC*NT]      = 80 KB
#define WS_LPART  5668864                   // float[BH*NC*NT]      = 80 KB

// =============== Kernel A: sampled scores -> M[bh*L + l] ===============
// 4 queries per wave: lane = qq*16 + dl, each lane holds float4 of Q.
// XCD swizzle keeps each head's K resident in one XCD's L2.
__global__ __launch_bounds__(256) void kM(const float* __restrict__ Q,
                                          const float* __restrict__ K,
                                          const int* __restrict__ idx,
                                          float* __restrict__ M)
{
    // blockIdx.x in [0,4096): xcd = b&7, slot = b>>3; head = (slot&3)*8+xcd
    int b    = blockIdx.x;
    int xcd  = b & 7;
    int slot = b >> 3;
    int head = (slot & 3) * 8 + xcd;
    int qc   = slot >> 2;                  // 0..127
    int wave = threadIdx.x >> 6;
    int lane = threadIdx.x & 63;
    int qq   = lane >> 4;
    int dl   = lane & 15;

    int l   = qc * 16 + wave * 4 + qq;     // query row within head
    int qid = head * L + l;

    float4 qv = reinterpret_cast<const float4*>(Q)[(size_t)qid * 16 + dl];
    const float4* K4 = reinterpret_cast<const float4*>(K) + (size_t)head * L * 16;

    float mx = -INFINITY, sm = 0.f;
    #pragma unroll 8
    for (int s = 0; s < SK; ++s) {
        int kr = idx[l * SK + s];
        float4 kv = K4[(size_t)kr * 16 + dl];
        float p = qv.x * kv.x + qv.y * kv.y + qv.z * kv.z + qv.w * kv.w;
        #pragma unroll
        for (int o = 1; o < 16; o <<= 1) p += __shfl_xor(p, o, 64);
        mx = fmaxf(mx, p);
        sm += p;
    }
    if (dl == 0) M[qid] = mx - sm * (1.0f / (float)L);
}

// =============== Kernel B: top-40 per head (one wave per block) ===============
__global__ __launch_bounds__(64) void kTop(const float* __restrict__ M, int* __restrict__ Mtop)
{
    __shared__ float sm[L];
    int bh = blockIdx.x;
    int t  = threadIdx.x;                  // 0..63
    for (int i = t; i < L; i += 64) sm[i] = M[bh * L + i];
    __syncthreads();
    for (int u = 0; u < NT; ++u) {
        float bv = -INFINITY; int bi = 0;
        for (int i = t; i < L; i += 64) {
            float v = sm[i];
            if (v > bv) { bv = v; bi = i; }    // increasing i => lowest local idx on tie
        }
        #pragma unroll
        for (int o = 1; o < 64; o <<= 1) {
            float ov = __shfl_xor(bv, o, 64);
            int   oi = __shfl_xor(bi, o, 64);
            if (ov > bv || (ov == bv && oi < bi)) { bv = ov; bi = oi; }
        }
        if (t == 0) { Mtop[bh * NT + u] = bi; sm[bi] = -INFINITY; }
        __syncthreads();
    }
}

// =============== Kernel C1/C2: per-head column mean of V ===============
__global__ __launch_bounds__(256) void kVmean1(const float* __restrict__ V,
                                               float* __restrict__ Vp)
{
    __shared__ float red[256];
    int b  = blockIdx.x;                   // bh*8 + c
    int bh = b >> 3, c = b & 7;
    int dl = threadIdx.x & 63;
    int g  = threadIdx.x >> 6;
    const float* Vb = V + (size_t)bh * L * D;
    float acc = 0.f;
    int base = c * 256 + g * 64;
    for (int k = 0; k < 64; ++k) acc += Vb[(size_t)(base + k) * D + dl];
    red[threadIdx.x] = acc;
    __syncthreads();
    if (threadIdx.x < 64)
        Vp[b * 64 + dl] = red[dl] + red[64 + dl] + red[128 + dl] + red[192 + dl];
}

__global__ __launch_bounds__(64) void kVmean2(const float* __restrict__ Vp,
                                              float* __restrict__ Vm)
{
    int bh = blockIdx.x, d = threadIdx.x;
    float s = 0.f;
    #pragma unroll
    for (int c = 0; c < 8; ++c) s += Vp[(bh * 8 + c) * 64 + d];
    Vm[bh * D + d] = s * (1.0f / (float)L);
}

// =============== Kernel D: broadcast V_mean into the whole output ===============
__global__ __launch_bounds__(256) void kFill(const float* __restrict__ Vm,
                                             float* __restrict__ out)
{
    int tid  = blockIdx.x * 256 + threadIdx.x;
    int base = tid * 4;
    int bh   = base >> 17;
    int d0   = base & (D - 1);
    float4 v = *reinterpret_cast<const float4*>(Vm + bh * D + d0);
    *reinterpret_cast<float4*>(out + base) = v;
}

// =============== Kernel E: split-K attention partials ===============
// grid (NC, BH), 256 threads. K chunk staged in LDS (XOR swizzle), all 40
// queries scored against it; chunk-local softmax; register-tiled PV.
__global__ __launch_bounds__(256, 2) void kAttnPart(const float* __restrict__ Q,
                                                    const float* __restrict__ K,
                                                    const float* __restrict__ V,
                                                    const int* __restrict__ Mtop,
                                                    float* __restrict__ Opart,
                                                    float* __restrict__ mpart,
                                                    float* __restrict__ lpart)
{
    __shared__ float4 KV4[CK * 16];        // 32 KB, swizzled, reused K then V
    __shared__ float4 Qs4[NT * 16];        // 10 KB
    __shared__ float  S[NT * CK];          // 20 KB, scores then exp(P)
    __shared__ int    mrow[NT];
    __shared__ float  smax[NT], ssum[NT];

    int c = blockIdx.x, bh = blockIdx.y;
    int t = threadIdx.x;

    if (t < NT) mrow[t] = Mtop[bh * NT + t];
    __syncthreads();

    // stage Q rows (gathered) and K chunk (swizzled)
    const float4* Qg = reinterpret_cast<const float4*>(Q) + (size_t)bh * L * 16;
    for (int i = t; i < NT * 16; i += 256) {
        int u = i >> 4, d4 = i & 15;
        Qs4[i] = Qg[(size_t)mrow[u] * 16 + d4];
    }
    const float4* Kg = reinterpret_cast<const float4*>(K) + ((size_t)bh * L + c * CK) * 16;
    for (int i = t; i < CK * 16; i += 256) {
        int j = i >> 4, d4 = i & 15;
        KV4[j * 16 + (d4 ^ (j & 15))] = Kg[i];
    }
    __syncthreads();

    // Phase A: S[u][j] = scale * q_u . k_j
    {
        int wave = t >> 6, lane = t & 63;
        int jh = wave & 1, uh = wave >> 1;       // j half, u half
        int j = jh * 64 + lane;
        float4 k4[16];
        #pragma unroll
        for (int d4 = 0; d4 < 16; ++d4) k4[d4] = KV4[j * 16 + (d4 ^ (j & 15))];
        for (int u = uh * 20; u < uh * 20 + 20; ++u) {
            float acc = 0.f;
            #pragma unroll
            for (int d4 = 0; d4 < 16; ++d4) {
                float4 q4 = Qs4[u * 16 + d4];
                acc += k4[d4].x * q4.x + k4[d4].y * q4.y
                     + k4[d4].z * q4.z + k4[d4].w * q4.w;
            }
            S[u * CK + j] = acc * SCALE;
        }
    }
    __syncthreads();

    // issue V loads early (latency overlaps softmax)
    const float4* Vg = reinterpret_cast<const float4*>(V) + ((size_t)bh * L + c * CK) * 16;
    float4 vreg[8];
    #pragma unroll
    for (int k = 0; k < 8; ++k) vreg[k] = Vg[t + k * 256];

    // chunk-local softmax: m,l per u; S <- exp(S - m)
    {
        int wave = t >> 6, lane = t & 63;
        for (int u = wave * 10; u < wave * 10 + 10; ++u) {
            float s0 = S[u * CK + lane], s1 = S[u * CK + 64 + lane];
            float m = fmaxf(s0, s1);
            #pragma unroll
            for (int o = 1; o < 64; o <<= 1) m = fmaxf(m, __shfl_xor(m, o, 64));
            float e0 = __expf(s0 - m), e1 = __expf(s1 - m);
            S[u * CK + lane] = e0; S[u * CK + 64 + lane] = e1;
            float l2 = e0 + e1;
            #pragma unroll
            for (int o = 1; o < 64; o <<= 1) l2 += __shfl_xor(l2, o, 64);
            if (lane == 0) { smax[u] = m; ssum[u] = l2; }
        }
    }
    __syncthreads();                       // S/ m/l done, K-LDS reads done

    // overwrite LDS with V chunk (swizzled)
    #pragma unroll
    for (int k = 0; k < 8; ++k) {
        int i = t + k * 256;
        int j = i >> 4, d4 = i & 15;
        KV4[j * 16 + (d4 ^ (j & 15))] = vreg[k];
    }
    __syncthreads();

    // Phase B: O[u][d] = sum_j P[u][j] V[j][d], register-tiled.
    // thread = (a in 0..7)*32 + (d4 in 0..15)*2 + (jh in 0..1); u = a + 8*ui
    {
        int a = t >> 5, r = t & 31;
        int d4 = r >> 1, jh = r & 1;
        float4 acc[5];
        #pragma unroll
        for (int ui = 0; ui < 5; ++ui) acc[ui] = make_float4(0.f, 0.f, 0.f, 0.f);
        for (int jj = 0; jj < 64; ++jj) {
            int j = jh * 64 + jj;
            float4 v4 = KV4[j * 16 + (d4 ^ (j & 15))];
            #pragma unroll
            for (int ui = 0; ui < 5; ++ui) {
                float p = S[(a + 8 * ui) * CK + j];
                acc[ui].x += p * v4.x; acc[ui].y += p * v4.y;
                acc[ui].z += p * v4.z; acc[ui].w += p * v4.w;
            }
        }
        // combine jh pairs (tid bit0)
        #pragma unroll
        for (int ui = 0; ui < 5; ++ui) {
            acc[ui].x += __shfl_xor(acc[ui].x, 1, 64);
            acc[ui].y += __shfl_xor(acc[ui].y, 1, 64);
            acc[ui].z += __shfl_xor(acc[ui].z, 1, 64);
            acc[ui].w += __shfl_xor(acc[ui].w, 1, 64);
        }
        if (jh == 0) {
            float4* Og = reinterpret_cast<float4*>(Opart) + ((size_t)(bh * NC + c) * NT) * 16;
            #pragma unroll
            for (int ui = 0; ui < 5; ++ui)
                Og[(a + 8 * ui) * 16 + d4] = acc[ui];
        }
    }
    if (t < NT) {
        mpart[(bh * NC + blockIdx.x) * NT + t] = smax[t];
        lpart[(bh * NC + blockIdx.x) * NT + t] = ssum[t];
    }
}

// =============== Kernel F: combine partials, overwrite selected rows ===============
__global__ __launch_bounds__(64) void kCombine(const float* __restrict__ Opart,
                                               const float* __restrict__ mpart,
                                               const float* __restrict__ lpart,
                                               const int* __restrict__ Mtop,
                                               float* __restrict__ out)
{
    int u = blockIdx.x, bh = blockIdx.y, d = threadIdx.x;
    float gm = -INFINITY, den = 0.f, o = 0.f;
    for (int c = 0; c < NC; ++c) {
        int pi = (bh * NC + c) * NT + u;
        float mv = mpart[pi], lv = lpart[pi];
        float nm = fmaxf(gm, mv);
        float r1 = __expf(gm - nm), r2 = __expf(mv - nm);
        o   = o * r1 + r2 * Opart[(size_t)pi * D + d];
        den = den * r1 + r2 * lv;
        gm  = nm;
    }
    int qrow = Mtop[bh * NT + u];
    out[((size_t)bh * L + qrow) * D + d] = o / den;
}

extern "C" void kernel_launch(void* const* d_in, const int* in_sizes, int n_in,
                              void* d_out, int out_size, void* d_ws, size_t ws_size,
                              hipStream_t stream)
{
    const float* Q   = (const float*)d_in[0];
    const float* K   = (const float*)d_in[1];
    const float* V   = (const float*)d_in[2];
    const int*   idx = (const int*)d_in[3];
    float* out = (float*)d_out;

    char* ws = (char*)d_ws;
    float* M     = (float*)(ws + WS_M);
    int*   Mtop  = (int*)  (ws + WS_MTOP);
    float* Vp    = (float*)(ws + WS_VP);
    float* Vm    = (float*)(ws + WS_VM);
    float* Opart = (float*)(ws + WS_OPART);
    float* mpart = (float*)(ws + WS_MPART);
    float* lpart = (float*)(ws + WS_LPART);

    kM      <<<4096, 256, 0, stream>>>(Q, K, idx, M);
    kTop    <<<BH, 64, 0, stream>>>(M, Mtop);
    kVmean1 <<<BH * 8, 256, 0, stream>>>(V, Vp);
    kVmean2 <<<BH, 64, 0, stream>>>(Vp, Vm);
    kFill   <<<(BH * L * D) / (4 * 256), 256, 0, stream>>>(Vm, out);
    kAttnPart<<<dim3(NC, BH), 256, 0, stream>>>(Q, K, V, Mtop, Opart, mpart, lpart);
    kCombine<<<dim3(NT, BH), 64, 0, stream>>>(Opart, mpart, lpart, Mtop, out);
}

// Round 4
// 175.986 us; speedup vs baseline: 4.5540x; 1.3931x over previous
//
#include <hip/hip_runtime.h>
#include <math.h>

#define BH 32
#define L  2048
#define D  64
#define SK 40
#define NT 40
#define NC 16          // key chunks for split-K attention
#define CK 128         // keys per chunk (NC*CK == L)
#define SCALE 0.125f

// ---- workspace layout (bytes) --- total ~5.75 MB ----
#define WS_M      0                         // float[BH*L]          = 256 KB
#define WS_MTOP   262144                    // int[BH*NT]           = 5 KB
#define WS_VP     267264                    // float[256*64]        = 64 KB
#define WS_VM     332800                    // float[BH*D]          = 8 KB
#define WS_OPART  344064                    // float[BH*NC*NT*D]    = 5.24 MB
#define WS_MPART  5586944                   // float[BH*NC*NT]      = 80 KB
#define WS_LPART  5668864                   // float[BH*NC*NT]      = 80 KB

// =============== Kernel A: sampled scores -> M[bh*L + l] ===============
// 4 queries per wave: lane = qq*16 + dl, each lane holds float4 of Q.
// XCD swizzle keeps each head's K resident in one XCD's L2.
__global__ __launch_bounds__(256) void kM(const float* __restrict__ Q,
                                          const float* __restrict__ K,
                                          const int* __restrict__ idx,
                                          float* __restrict__ M)
{
    __shared__ int sidx[16 * SK];
    // blockIdx.x in [0,4096): xcd = b&7, slot = b>>3; head = (slot&3)*8+xcd
    int b    = blockIdx.x;
    int xcd  = b & 7;
    int slot = b >> 3;
    int head = (slot & 3) * 8 + xcd;
    int qc   = slot >> 2;                  // 0..127
    int wave = threadIdx.x >> 6;
    int lane = threadIdx.x & 63;
    int qq   = lane >> 4;
    int dl   = lane & 15;

    int l0 = qc * 16;
    for (int i = threadIdx.x; i < 16 * SK; i += 256)
        sidx[i] = idx[(l0 + i / SK) * SK + (i % SK)];
    __syncthreads();

    int lq  = wave * 4 + qq;               // 0..15 within block
    int l   = l0 + lq;                     // query row within head
    int qid = head * L + l;

    float4 qv = reinterpret_cast<const float4*>(Q)[(size_t)qid * 16 + dl];
    const float4* K4 = reinterpret_cast<const float4*>(K) + (size_t)head * L * 16;

    float mx = -INFINITY, sm = 0.f;
    #pragma unroll 8
    for (int s = 0; s < SK; ++s) {
        int kr = sidx[lq * SK + s];
        float4 kv = K4[(size_t)kr * 16 + dl];
        float p = qv.x * kv.x + qv.y * kv.y + qv.z * kv.z + qv.w * kv.w;
        #pragma unroll
        for (int o = 1; o < 16; o <<= 1) p += __shfl_xor(p, o, 64);
        mx = fmaxf(mx, p);
        sm += p;
    }
    if (dl == 0) M[qid] = mx - sm * (1.0f / (float)L);
}

// =============== Kernel B: top-40 per head via 4-round radix select ===============
// One 256-thread block per head. Keys = monotone uint32 map of fp32.
// After 4 rounds T = exact 40th-largest key; take all >T plus lowest-index ties.
__global__ __launch_bounds__(256) void kTop(const float* __restrict__ M, int* __restrict__ Mtop)
{
    __shared__ unsigned int keys[L];
    __shared__ int hist[256];
    __shared__ int ssum[256];
    __shared__ int bsel;
    __shared__ unsigned int pref_s;
    __shared__ int krem_s;
    __shared__ int cnt_gt, cnt_eq;
    __shared__ int eqlist[64];

    int bh = blockIdx.x;
    int t  = threadIdx.x;

    for (int i = t; i < L; i += 256) {
        unsigned int u = __float_as_uint(M[bh * L + i]);
        keys[i] = (u & 0x80000000u) ? ~u : (u | 0x80000000u);
    }
    if (t == 0) { pref_s = 0u; krem_s = NT; cnt_gt = 0; cnt_eq = 0; }
    __syncthreads();

    #pragma unroll
    for (int shift = 24; shift >= 0; shift -= 8) {
        hist[t] = 0;
        __syncthreads();
        unsigned int pref = pref_s;
        for (int i = t; i < L; i += 256) {
            unsigned int k  = keys[i];
            unsigned int hi = (shift == 24) ? 0u : (k >> (shift + 8));
            if (hi == pref) atomicAdd(&hist[(k >> shift) & 0xFF], 1);
        }
        __syncthreads();
        ssum[t] = hist[t];                       // suffix-sum (inclusive)
        __syncthreads();
        for (int st = 1; st < 256; st <<= 1) {
            int v = (t + st < 256) ? ssum[t + st] : 0;
            __syncthreads();
            ssum[t] += v;
            __syncthreads();
        }
        int krem = krem_s;
        int excl = ssum[t] - hist[t];            // count of keys with byte > t
        if (excl < krem && excl + hist[t] >= krem) bsel = t;
        __syncthreads();
        if (t == 0) {
            int bb = bsel;
            krem_s = krem_s - (ssum[bb] - hist[bb]);
            pref_s = (pref_s << 8) | (unsigned int)bb;
        }
        __syncthreads();
    }

    unsigned int T = pref_s;
    int krem = krem_s;
    for (int i = t; i < L; i += 256) {
        unsigned int k = keys[i];
        if (k > T) {
            int p = atomicAdd(&cnt_gt, 1);
            Mtop[bh * NT + p] = i;               // order within Mtop is irrelevant (scatter set)
        } else if (k == T) {
            int p = atomicAdd(&cnt_eq, 1);
            if (p < 64) eqlist[p] = i;
        }
    }
    __syncthreads();
    if (t == 0) {
        int base = cnt_gt;                       // == NT - krem
        int m = cnt_eq < 64 ? cnt_eq : 64;
        for (int q = 0; q < krem; ++q) {         // lowest-index ties, matching top_k
            int best = 0x7fffffff, bj = -1;
            for (int j = 0; j < m; ++j) if (eqlist[j] < best) { best = eqlist[j]; bj = j; }
            Mtop[bh * NT + base + q] = best;
            if (bj >= 0) eqlist[bj] = 0x7fffffff;
        }
    }
}

// =============== Kernel C1/C2: per-head column mean of V ===============
__global__ __launch_bounds__(256) void kVmean1(const float* __restrict__ V,
                                               float* __restrict__ Vp)
{
    __shared__ float red[256];
    int b  = blockIdx.x;                   // bh*8 + c
    int bh = b >> 3, c = b & 7;
    int dl = threadIdx.x & 63;
    int g  = threadIdx.x >> 6;
    const float* Vb = V + (size_t)bh * L * D;
    float acc = 0.f;
    int base = c * 256 + g * 64;
    for (int k = 0; k < 64; ++k) acc += Vb[(size_t)(base + k) * D + dl];
    red[threadIdx.x] = acc;
    __syncthreads();
    if (threadIdx.x < 64)
        Vp[b * 64 + dl] = red[dl] + red[64 + dl] + red[128 + dl] + red[192 + dl];
}

__global__ __launch_bounds__(64) void kVmean2(const float* __restrict__ Vp,
                                              float* __restrict__ Vm)
{
    int bh = blockIdx.x, d = threadIdx.x;
    float s = 0.f;
    #pragma unroll
    for (int c = 0; c < 8; ++c) s += Vp[(bh * 8 + c) * 64 + d];
    Vm[bh * D + d] = s * (1.0f / (float)L);
}

// =============== Kernel D: broadcast V_mean into the whole output ===============
__global__ __launch_bounds__(256) void kFill(const float* __restrict__ Vm,
                                             float* __restrict__ out)
{
    int tid  = blockIdx.x * 256 + threadIdx.x;
    int base = tid * 4;
    int bh   = base >> 17;
    int d0   = base & (D - 1);
    float4 v = *reinterpret_cast<const float4*>(Vm + bh * D + d0);
    *reinterpret_cast<float4*>(out + base) = v;
}

// =============== Kernel E: split-K attention partials ===============
// grid (NC, BH), 256 threads. K chunk staged in LDS (XOR swizzle), all 40
// queries scored against it; chunk-local softmax; register-tiled PV.
__global__ __launch_bounds__(256, 2) void kAttnPart(const float* __restrict__ Q,
                                                    const float* __restrict__ K,
                                                    const float* __restrict__ V,
                                                    const int* __restrict__ Mtop,
                                                    float* __restrict__ Opart,
                                                    float* __restrict__ mpart,
                                                    float* __restrict__ lpart)
{
    __shared__ float4 KV4[CK * 16];        // 32 KB, swizzled, reused K then V
    __shared__ float4 Qs4[NT * 16];        // 10 KB
    __shared__ float  S[NT * CK];          // 20 KB, scores then exp(P)
    __shared__ int    mrow[NT];
    __shared__ float  smax[NT], ssum[NT];

    int c = blockIdx.x, bh = blockIdx.y;
    int t = threadIdx.x;

    if (t < NT) mrow[t] = Mtop[bh * NT + t];
    __syncthreads();

    // stage Q rows (gathered) and K chunk (swizzled)
    const float4* Qg = reinterpret_cast<const float4*>(Q) + (size_t)bh * L * 16;
    for (int i = t; i < NT * 16; i += 256) {
        int u = i >> 4, d4 = i & 15;
        Qs4[i] = Qg[(size_t)mrow[u] * 16 + d4];
    }
    const float4* Kg = reinterpret_cast<const float4*>(K) + ((size_t)bh * L + c * CK) * 16;
    for (int i = t; i < CK * 16; i += 256) {
        int j = i >> 4, d4 = i & 15;
        KV4[j * 16 + (d4 ^ (j & 15))] = Kg[i];
    }
    __syncthreads();

    // Phase A: S[u][j] = scale * q_u . k_j
    {
        int wave = t >> 6, lane = t & 63;
        int jh = wave & 1, uh = wave >> 1;       // j half, u half
        int j = jh * 64 + lane;
        float4 k4[16];
        #pragma unroll
        for (int d4 = 0; d4 < 16; ++d4) k4[d4] = KV4[j * 16 + (d4 ^ (j & 15))];
        for (int u = uh * 20; u < uh * 20 + 20; ++u) {
            float acc = 0.f;
            #pragma unroll
            for (int d4 = 0; d4 < 16; ++d4) {
                float4 q4 = Qs4[u * 16 + d4];
                acc += k4[d4].x * q4.x + k4[d4].y * q4.y
                     + k4[d4].z * q4.z + k4[d4].w * q4.w;
            }
            S[u * CK + j] = acc * SCALE;
        }
    }
    __syncthreads();

    // issue V loads early (latency overlaps softmax)
    const float4* Vg = reinterpret_cast<const float4*>(V) + ((size_t)bh * L + c * CK) * 16;
    float4 vreg[8];
    #pragma unroll
    for (int k = 0; k < 8; ++k) vreg[k] = Vg[t + k * 256];

    // chunk-local softmax: m,l per u; S <- exp(S - m)
    {
        int wave = t >> 6, lane = t & 63;
        for (int u = wave * 10; u < wave * 10 + 10; ++u) {
            float s0 = S[u * CK + lane], s1 = S[u * CK + 64 + lane];
            float m = fmaxf(s0, s1);
            #pragma unroll
            for (int o = 1; o < 64; o <<= 1) m = fmaxf(m, __shfl_xor(m, o, 64));
            float e0 = __expf(s0 - m), e1 = __expf(s1 - m);
            S[u * CK + lane] = e0; S[u * CK + 64 + lane] = e1;
            float l2 = e0 + e1;
            #pragma unroll
            for (int o = 1; o < 64; o <<= 1) l2 += __shfl_xor(l2, o, 64);
            if (lane == 0) { smax[u] = m; ssum[u] = l2; }
        }
    }
    __syncthreads();                       // S/ m/l done, K-LDS reads done

    // overwrite LDS with V chunk (swizzled)
    #pragma unroll
    for (int k = 0; k < 8; ++k) {
        int i = t + k * 256;
        int j = i >> 4, d4 = i & 15;
        KV4[j * 16 + (d4 ^ (j & 15))] = vreg[k];
    }
    __syncthreads();

    // Phase B: O[u][d] = sum_j P[u][j] V[j][d], register-tiled.
    // thread = (a in 0..7)*32 + (d4 in 0..15)*2 + (jh in 0..1); u = a + 8*ui
    {
        int a = t >> 5, r = t & 31;
        int d4 = r >> 1, jh = r & 1;
        float4 acc[5];
        #pragma unroll
        for (int ui = 0; ui < 5; ++ui) acc[ui] = make_float4(0.f, 0.f, 0.f, 0.f);
        for (int jj = 0; jj < 64; ++jj) {
            int j = jh * 64 + jj;
            float4 v4 = KV4[j * 16 + (d4 ^ (j & 15))];
            #pragma unroll
            for (int ui = 0; ui < 5; ++ui) {
                float p = S[(a + 8 * ui) * CK + j];
                acc[ui].x += p * v4.x; acc[ui].y += p * v4.y;
                acc[ui].z += p * v4.z; acc[ui].w += p * v4.w;
            }
        }
        // combine jh pairs (tid bit0)
        #pragma unroll
        for (int ui = 0; ui < 5; ++ui) {
            acc[ui].x += __shfl_xor(acc[ui].x, 1, 64);
            acc[ui].y += __shfl_xor(acc[ui].y, 1, 64);
            acc[ui].z += __shfl_xor(acc[ui].z, 1, 64);
            acc[ui].w += __shfl_xor(acc[ui].w, 1, 64);
        }
        if (jh == 0) {
            float4* Og = reinterpret_cast<float4*>(Opart) + ((size_t)(bh * NC + c) * NT) * 16;
            #pragma unroll
            for (int ui = 0; ui < 5; ++ui)
                Og[(a + 8 * ui) * 16 + d4] = acc[ui];
        }
    }
    if (t < NT) {
        mpart[(bh * NC + blockIdx.x) * NT + t] = smax[t];
        lpart[(bh * NC + blockIdx.x) * NT + t] = ssum[t];
    }
}

// =============== Kernel F: combine partials, overwrite selected rows ===============
__global__ __launch_bounds__(64) void kCombine(const float* __restrict__ Opart,
                                               const float* __restrict__ mpart,
                                               const float* __restrict__ lpart,
                                               const int* __restrict__ Mtop,
                                               float* __restrict__ out)
{
    int u = blockIdx.x, bh = blockIdx.y, d = threadIdx.x;
    float gm = -INFINITY, den = 0.f, o = 0.f;
    for (int c = 0; c < NC; ++c) {
        int pi = (bh * NC + c) * NT + u;
        float mv = mpart[pi], lv = lpart[pi];
        float nm = fmaxf(gm, mv);
        float r1 = __expf(gm - nm), r2 = __expf(mv - nm);
        o   = o * r1 + r2 * Opart[(size_t)pi * D + d];
        den = den * r1 + r2 * lv;
        gm  = nm;
    }
    int qrow = Mtop[bh * NT + u];
    out[((size_t)bh * L + qrow) * D + d] = o / den;
}

extern "C" void kernel_launch(void* const* d_in, const int* in_sizes, int n_in,
                              void* d_out, int out_size, void* d_ws, size_t ws_size,
                              hipStream_t stream)
{
    const float* Q   = (const float*)d_in[0];
    const float* K   = (const float*)d_in[1];
    const float* V   = (const float*)d_in[2];
    const int*   idx = (const int*)d_in[3];
    float* out = (float*)d_out;

    char* ws = (char*)d_ws;
    float* M     = (float*)(ws + WS_M);
    int*   Mtop  = (int*)  (ws + WS_MTOP);
    float* Vp    = (float*)(ws + WS_VP);
    float* Vm    = (float*)(ws + WS_VM);
    float* Opart = (float*)(ws + WS_OPART);
    float* mpart = (float*)(ws + WS_MPART);
    float* lpart = (float*)(ws + WS_LPART);

    kM      <<<4096, 256, 0, stream>>>(Q, K, idx, M);
    kTop    <<<BH, 256, 0, stream>>>(M, Mtop);
    kVmean1 <<<BH * 8, 256, 0, stream>>>(V, Vp);
    kVmean2 <<<BH, 64, 0, stream>>>(Vp, Vm);
    kFill   <<<(BH * L * D) / (4 * 256), 256, 0, stream>>>(Vm, out);
    kAttnPart<<<dim3(NC, BH), 256, 0, stream>>>(Q, K, V, Mtop, Opart, mpart, lpart);
    kCombine<<<dim3(NT, BH), 64, 0, stream>>>(Opart, mpart, lpart, Mtop, out);
}